// Round 1
// baseline (30405.460 us; speedup 1.0000x reference)
//
#include <hip/hip_runtime.h>
#include <hip/hip_bf16.h>
#include <stdint.h>

#define T_STEPS 4096
#define BATCH 32
#define IDIM 512
#define HDIM 512
#define CDIM 128

typedef float f32x4 __attribute__((ext_vector_type(4)));
typedef short s16x8 __attribute__((ext_vector_type(8)));
typedef unsigned short u16x4 __attribute__((ext_vector_type(4)));

__device__ __forceinline__ unsigned short f2bf(float f) {
    union { float f; uint32_t u; } v; v.f = f;
    uint32_t r = v.u + 0x7fffu + ((v.u >> 16) & 1u);  // RNE
    return (unsigned short)(r >> 16);
}
__device__ __forceinline__ float bf2f(unsigned short s) {
    union { uint32_t u; float f; } v; v.u = ((uint32_t)s) << 16;
    return v.f;
}

// ---------------------------------------------------------------------------
// Kernel 1: transpose W_hh [H][H] fp32 -> WT[i][j] = W_hh[j][i]
// ---------------------------------------------------------------------------
__global__ void transpose_whh(const float* __restrict__ W, float* __restrict__ WT) {
    __shared__ float tile[32][33];
    const int tx = threadIdx.x, ty = threadIdx.y;
    const int bx = blockIdx.x, by = blockIdx.y;
    int x = bx * 32 + tx;                 // i coord in W (column)
    #pragma unroll
    for (int k = 0; k < 32; k += 8) {
        int y = by * 32 + ty + k;         // j coord in W (row)
        tile[ty + k][tx] = W[(size_t)y * HDIM + x];
    }
    __syncthreads();
    #pragma unroll
    for (int k = 0; k < 32; k += 8) {
        int i_out = bx * 32 + ty + k;
        int j_out = by * 32 + tx;
        WT[(size_t)i_out * HDIM + j_out] = tile[tx][ty + k];
    }
}

// ---------------------------------------------------------------------------
// Kernel 2: A[m][n] = bf16( X[m][:] . Wih[n][:] + bih[n] + bhh[n] )
// M = tc*BATCH rows (chunk), N = HDIM, K = IDIM. bf16 MFMA 16x16x32.
// Tile 128x128, 4 waves in 2x2 grid, each wave 64x64 (4x4 fragments).
// ---------------------------------------------------------------------------
__global__ __launch_bounds__(256) void xih_gemm(
    const float* __restrict__ X,    // [M][K] fp32
    const float* __restrict__ Wih,  // [N][K] fp32
    const float* __restrict__ bih,
    const float* __restrict__ bhh,
    unsigned short* __restrict__ A) // [M][N] bf16 bits
{
    __shared__ __align__(16) unsigned short As[128][40];
    __shared__ __align__(16) unsigned short Bs[128][40];

    const int tid  = threadIdx.x;
    const int lane = tid & 63;
    const int wave = tid >> 6;
    const int wr = wave >> 1, wc = wave & 1;
    const int row0 = blockIdx.y * 128;   // m
    const int col0 = blockIdx.x * 128;   // n
    const int l16 = lane & 15, lhi = lane >> 4;

    const int lr = tid >> 3;   // 0..31: row within 32-row staging group
    const int kf = tid & 7;    // float4 index within 32 k's

    f32x4 acc[4][4] = {};

    for (int k0 = 0; k0 < IDIM; k0 += 32) {
        // ---- stage 128x32 of X and Wih into LDS as bf16 ----
        #pragma unroll
        for (int rr = 0; rr < 128; rr += 32) {
            int r = lr + rr;
            float4 xv = *(const float4*)&X[(size_t)(row0 + r) * IDIM + k0 + kf * 4];
            float4 wv = *(const float4*)&Wih[(size_t)(col0 + r) * IDIM + k0 + kf * 4];
            u16x4 xq, wq;
            xq.x = f2bf(xv.x); xq.y = f2bf(xv.y); xq.z = f2bf(xv.z); xq.w = f2bf(xv.w);
            wq.x = f2bf(wv.x); wq.y = f2bf(wv.y); wq.z = f2bf(wv.z); wq.w = f2bf(wv.w);
            *(u16x4*)&As[r][kf * 4] = xq;
            *(u16x4*)&Bs[r][kf * 4] = wq;
        }
        __syncthreads();

        // ---- fragments + MFMA ----
        s16x8 af[4], bfr[4];
        #pragma unroll
        for (int mi = 0; mi < 4; ++mi)
            af[mi] = *(const s16x8*)&As[wr * 64 + mi * 16 + l16][lhi * 8];
        #pragma unroll
        for (int ni = 0; ni < 4; ++ni)
            bfr[ni] = *(const s16x8*)&Bs[wc * 64 + ni * 16 + l16][lhi * 8];
        #pragma unroll
        for (int mi = 0; mi < 4; ++mi)
            #pragma unroll
            for (int ni = 0; ni < 4; ++ni)
                acc[mi][ni] = __builtin_amdgcn_mfma_f32_16x16x32_bf16(
                    af[mi], bfr[ni], acc[mi][ni], 0, 0, 0);
        __syncthreads();
    }

    // ---- epilogue: add bias, store bf16 ----
    #pragma unroll
    for (int ni = 0; ni < 4; ++ni) {
        int col = col0 + wc * 64 + ni * 16 + l16;
        float bias = bih[col] + bhh[col];
        #pragma unroll
        for (int mi = 0; mi < 4; ++mi) {
            int rowb = row0 + wr * 64 + mi * 16 + lhi * 4;
            #pragma unroll
            for (int r = 0; r < 4; ++r)
                A[(size_t)(rowb + r) * HDIM + col] = f2bf(acc[mi][ni][r] + bias);
        }
    }
}

// ---------------------------------------------------------------------------
// Kernel 3: persistent per-batch recurrence over tc steps.
// 32 workgroups (one per batch), 512 threads: thread = (4 cols) x (K-quarter).
// h kept in LDS; W_hh^T streamed fp32 (L2-resident after step 0).
// State carried in global hstate; final chunk also does the fused FC.
// ---------------------------------------------------------------------------
__global__ __launch_bounds__(512) void rnn_scan(
    const unsigned short* __restrict__ A,  // [tc][BATCH][HDIM] bf16 bits
    const float* __restrict__ WT,          // [HDIM][HDIM]: WT[i][j] = Whh[j][i]
    const float* __restrict__ Wfc,         // [CDIM][HDIM]
    const float* __restrict__ bfc,         // [CDIM]
    float* __restrict__ out,               // [BATCH][CDIM]
    float* __restrict__ hstate,            // [BATCH][HDIM]
    int tc, int do_fc)
{
    __shared__ __align__(16) float hs[HDIM];
    __shared__ __align__(16) float ps[4][HDIM];

    const int b   = blockIdx.x;
    const int tid = threadIdx.x;
    const int j4  = tid & 127;     // column group
    const int q   = tid >> 7;      // K quarter 0..3
    const int c4  = j4 * 4;        // first of 4 owned columns
    const int iq0 = q * 128;       // K range start

    hs[tid] = hstate[b * HDIM + tid];
    __syncthreads();

    const unsigned short* Ab = A + (size_t)b * HDIM + tid;

    for (int t = 0; t < tc; ++t) {
        // prefetch this thread's additive term (used at step end)
        float a_t = bf2f(Ab[(size_t)t * (BATCH * HDIM)]);

        float acc0 = 0.f, acc1 = 0.f, acc2 = 0.f, acc3 = 0.f;
        const float* wp = WT + (size_t)iq0 * HDIM + c4;
        #pragma unroll 4
        for (int i = 0; i < 128; i += 4) {
            float4 hv = *(const float4*)&hs[iq0 + i];
            float4 w0 = *(const float4*)(wp + 0 * HDIM);
            float4 w1 = *(const float4*)(wp + 1 * HDIM);
            float4 w2 = *(const float4*)(wp + 2 * HDIM);
            float4 w3 = *(const float4*)(wp + 3 * HDIM);
            acc0 += w0.x * hv.x; acc1 += w0.y * hv.x; acc2 += w0.z * hv.x; acc3 += w0.w * hv.x;
            acc0 += w1.x * hv.y; acc1 += w1.y * hv.y; acc2 += w1.z * hv.y; acc3 += w1.w * hv.y;
            acc0 += w2.x * hv.z; acc1 += w2.y * hv.z; acc2 += w2.z * hv.z; acc3 += w2.w * hv.z;
            acc0 += w3.x * hv.w; acc1 += w3.y * hv.w; acc2 += w3.z * hv.w; acc3 += w3.w * hv.w;
            wp += 4 * HDIM;
        }
        float4 st; st.x = acc0; st.y = acc1; st.z = acc2; st.w = acc3;
        *(float4*)&ps[q][c4] = st;
        __syncthreads();                    // all hs reads + ps writes done
        float v = ps[0][tid] + ps[1][tid] + ps[2][tid] + ps[3][tid] + a_t;
        hs[tid] = fmaxf(v, 0.f);
        __syncthreads();                    // hs update visible for next step
    }

    hstate[b * HDIM + tid] = hs[tid];

    if (do_fc) {
        // out[b][c] = bfc[c] + sum_i hs[i] * Wfc[c][i]
        const int c  = tid & (CDIM - 1);
        const int fq = tid >> 7;           // i-quarter
        float facc = 0.f;
        #pragma unroll 4
        for (int i = fq * 128; i < fq * 128 + 128; i += 4) {
            float4 hv = *(const float4*)&hs[i];
            float4 w  = *(const float4*)&Wfc[(size_t)c * HDIM + i];
            facc += hv.x * w.x + hv.y * w.y + hv.z * w.z + hv.w * w.w;
        }
        __syncthreads();
        ps[fq][c] = facc;
        __syncthreads();
        if (fq == 0)
            out[b * CDIM + c] = ps[0][c] + ps[1][c] + ps[2][c] + ps[3][c] + bfc[c];
    }
}

// ---------------------------------------------------------------------------
extern "C" void kernel_launch(void* const* d_in, const int* in_sizes, int n_in,
                              void* d_out, int out_size, void* d_ws, size_t ws_size,
                              hipStream_t stream) {
    const float* x   = (const float*)d_in[0];  // [T][B][I]
    const float* h0  = (const float*)d_in[1];  // [B][H]
    const float* Wih = (const float*)d_in[2];  // [H][I]
    const float* bih = (const float*)d_in[3];  // [H]
    const float* Whh = (const float*)d_in[4];  // [H][H]
    const float* bhh = (const float*)d_in[5];  // [H]
    const float* Wfc = (const float*)d_in[6];  // [C][H]
    const float* bfc = (const float*)d_in[7];  // [C]

    float* out  = (float*)d_out;               // [B][C]
    float* hfin = out + BATCH * CDIM;          // [B][H] (2nd output, doubles as state)

    float* WT = (float*)d_ws;                                  // 1 MB
    const size_t wt_bytes = (size_t)HDIM * HDIM * sizeof(float);
    unsigned short* Abuf = (unsigned short*)((char*)d_ws + wt_bytes);

    // chunk T so the A buffer fits in workspace
    const size_t per_t = (size_t)BATCH * HDIM * sizeof(unsigned short); // 32 KB
    size_t avail = ws_size > wt_bytes ? ws_size - wt_bytes : 0;
    long long tcl = (long long)(avail / per_t);
    if (tcl > T_STEPS) tcl = T_STEPS;
    int TC = (int)(tcl & ~3LL);
    if (TC < 4) TC = 4;  // nothing sane possible below this; assume ws is adequate

    transpose_whh<<<dim3(16, 16), dim3(32, 8), 0, stream>>>(Whh, WT);
    hipMemcpyAsync(hfin, h0, (size_t)BATCH * HDIM * sizeof(float),
                   hipMemcpyDeviceToDevice, stream);

    for (int t0 = 0; t0 < T_STEPS; t0 += TC) {
        int tc = T_STEPS - t0 < TC ? T_STEPS - t0 : TC;
        xih_gemm<<<dim3(4, tc * BATCH / 128), 256, 0, stream>>>(
            x + (size_t)t0 * BATCH * IDIM, Wih, bih, bhh, Abuf);
        int do_fc = (t0 + tc >= T_STEPS) ? 1 : 0;
        rnn_scan<<<BATCH, 512, 0, stream>>>(Abuf, WT, Wfc, bfc, out, hfin, tc, do_fc);
    }
}